// Round 2
// baseline (315.034 us; speedup 1.0000x reference)
//
#include <hip/hip_runtime.h>

// Problem constants
#define T_ 64
#define P_ 144          // 12*12 windows per frame
#define NPAIR 9216      // T_*P_
#define C_ 1024
#define MID_ 256

typedef __attribute__((ext_vector_type(4))) float f32x4;
typedef __attribute__((ext_vector_type(8))) __bf16 bf16x8;
typedef __attribute__((ext_vector_type(4))) __bf16 bf16x4;

__device__ __forceinline__ void async_copy16(const void* g, void* l) {
  __builtin_amdgcn_global_load_lds(
      (const __attribute__((address_space(1))) unsigned int*)g,
      (__attribute__((address_space(3))) unsigned int*)l, 16, 0, 0);
}

// img row for global K-GEMM row g = 4*pair + w
__device__ __forceinline__ int img_row_of(int g) {
  const int pair = g >> 2;
  const int w = g & 3;
  const int t = pair / P_;
  const int pp = pair - t * P_;
  const int wy = pp / 12, wx = pp - wy * 12;
  return t * 576 + 48 * wy + 2 * wx + (w >> 1) * 24 + (w & 1);
}

// ---------------------------------------------------------------------------
// K1: blocks [0,NPAIR): mean-pool 2x2 windows -> pooled bf16.
//     blocks [NPAIR, NPAIR+512): transpose+convert Wq/Wk -> [256x1024] bf16.
__global__ void prep_kernel(const float* __restrict__ img,
                            const float* __restrict__ Wq,
                            const float* __restrict__ Wk,
                            __bf16* __restrict__ poolb,
                            __bf16* __restrict__ Wqt,
                            __bf16* __restrict__ Wkt) {
  const int bid = blockIdx.x;
  const int tid = threadIdx.x;
  if (bid < NPAIR) {
    const int t = bid / P_;
    const int p = bid - t * P_;
    const int wy = p / 12, wx = p - wy * 12;
    const int c = tid * 4;
    const float* base = img + ((size_t)t * 576 + 48 * wy + 2 * wx) * C_;
    f32x4 s = *(const f32x4*)(base + c);
    s += *(const f32x4*)(base + (size_t)1 * C_ + c);
    s += *(const f32x4*)(base + (size_t)24 * C_ + c);
    s += *(const f32x4*)(base + (size_t)25 * C_ + c);
    s *= 0.25f;
    bf16x4 pv;
#pragma unroll
    for (int j = 0; j < 4; ++j) pv[j] = (__bf16)s[j];
    *(bf16x4*)(poolb + (size_t)bid * C_ + c) = pv;
  } else {
    __shared__ float tl[32][33];
    const int b = bid - NPAIR;          // 0..511
    const int bx = b & 31;              // k-tile
    const int by = (b >> 5) & 7;        // n-tile
    const int bz = b >> 8;              // 0=Wq, 1=Wk
    const float* src = bz ? Wk : Wq;
    __bf16* dst = bz ? Wkt : Wqt;
    const int tx = tid & 31, ty = tid >> 5;  // 32 x 8
    const int k0 = bx * 32, n0 = by * 32;
#pragma unroll
    for (int i = 0; i < 32; i += 8)
      tl[ty + i][tx] = src[(size_t)(k0 + ty + i) * MID_ + n0 + tx];
    __syncthreads();
#pragma unroll
    for (int i = 0; i < 32; i += 8)
      dst[(size_t)(n0 + ty + i) * C_ + k0 + tx] = (__bf16)tl[tx][ty + i];
  }
}

// ---------------------------------------------------------------------------
// shared MFMA tile step (128x128, BK=32, 4 waves 2x2, 4x4 frags)
__device__ __forceinline__ void mfma_tile(const __bf16* As, const __bf16* Bs,
                                          int wm, int wn, int quad, int lr,
                                          f32x4 acc[4][4]) {
  bf16x8 a[4], b[4];
  const bf16x8* Ap = (const bf16x8*)As;
  const bf16x8* Bp = (const bf16x8*)Bs;
#pragma unroll
  for (int i = 0; i < 4; ++i) {
    a[i] = Ap[(wm * 64 + i * 16 + lr) * 4 + quad];
    b[i] = Bp[(wn * 64 + i * 16 + lr) * 4 + quad];
  }
#pragma unroll
  for (int mi = 0; mi < 4; ++mi)
#pragma unroll
    for (int ni = 0; ni < 4; ++ni)
      acc[mi][ni] = __builtin_amdgcn_mfma_f32_16x16x32_bf16(
          a[mi], b[ni], acc[mi][ni], 0, 0, 0);
}

// ---------------------------------------------------------------------------
// K2: merged GEMM. blocks 0..143:  Q[9216x256]  = pooled@Wq + bq  (bf16 out)
//                  blocks 144..719: K[36864x256] = windows@Wk + bk (bf16 out)
// K-part A is staged straight from fp32 img via the window row permutation.
__global__ __launch_bounds__(256) void gemm_qk_kernel(
    const __bf16* __restrict__ poolb, const float* __restrict__ img,
    const __bf16* __restrict__ Bqt, const __bf16* __restrict__ Bkt,
    const float* __restrict__ bq, const float* __restrict__ bk,
    __bf16* __restrict__ Qb, __bf16* __restrict__ Kb) {
  __shared__ __align__(16) __bf16 As[128 * 32];
  __shared__ __align__(16) __bf16 Bs[128 * 32];
  const int bid = blockIdx.x;
  const bool isQ = bid < 144;
  const __bf16* Bt;
  const float* bias;
  __bf16* Cout;
  int mt, nt;
  if (isQ) {
    Bt = Bqt; bias = bq; Cout = Qb;
    mt = bid >> 1; nt = bid & 1;
  } else {
    const int b = bid - 144;
    Bt = Bkt; bias = bk; Cout = Kb;
    mt = b >> 1; nt = b & 1;
  }
  const int tid = threadIdx.x;
  const int lane = tid & 63;
  const int wv = tid >> 6;
  const int quad = lane >> 4, lr = lane & 15;
  const int wm = wv >> 1, wn = wv & 1;

  const int r0 = tid >> 2, p0 = tid & 3;  // chunk: row r0 (+64), 16B piece p0
  const int wvb = (tid & ~63) * 16;       // wave-uniform LDS byte offset
  // B staging (always async from bf16 Wt)
  const __bf16* gb0 = Bt + ((size_t)nt * 128 + r0) * (size_t)C_ + p0 * 8;
  const __bf16* gb1 = gb0 + (size_t)64 * C_;
  char* BsB0 = (char*)Bs + wvb;
  char* BsB1 = (char*)Bs + 4096 + wvb;

  f32x4 acc[4][4] = {};

  if (isQ) {
    const __bf16* ga0 = poolb + ((size_t)mt * 128 + r0) * (size_t)C_ + p0 * 8;
    const __bf16* ga1 = ga0 + (size_t)64 * C_;
    char* AsB0 = (char*)As + wvb;
    char* AsB1 = (char*)As + 4096 + wvb;
    for (int it = 0; it < 32; ++it) {
      async_copy16(ga0, AsB0);
      async_copy16(ga1, AsB1);
      async_copy16(gb0, BsB0);
      async_copy16(gb1, BsB1);
      ga0 += 32; ga1 += 32; gb0 += 32; gb1 += 32;
      __syncthreads();
      mfma_tile(As, Bs, wm, wn, quad, lr, acc);
      __syncthreads();
    }
  } else {
    // A rows come from img (fp32) via window permutation; row is loop-invariant
    const int g0 = mt * 128 + r0;
    const float* fa0 = img + (size_t)img_row_of(g0) * C_ + p0 * 8;
    const float* fa1 = img + (size_t)img_row_of(g0 + 64) * C_ + p0 * 8;
    __bf16* lw0 = As + (size_t)tid * 8;
    __bf16* lw1 = As + (size_t)(tid + 256) * 8;
    for (int it = 0; it < 32; ++it) {
      const f32x4 u0 = *(const f32x4*)fa0;
      const f32x4 u1 = *(const f32x4*)(fa0 + 4);
      const f32x4 u2 = *(const f32x4*)fa1;
      const f32x4 u3 = *(const f32x4*)(fa1 + 4);
      fa0 += 32; fa1 += 32;
      bf16x8 c0, c1;
#pragma unroll
      for (int j = 0; j < 4; ++j) {
        c0[j] = (__bf16)u0[j]; c0[4 + j] = (__bf16)u1[j];
        c1[j] = (__bf16)u2[j]; c1[4 + j] = (__bf16)u3[j];
      }
      *(bf16x8*)lw0 = c0;
      *(bf16x8*)lw1 = c1;
      async_copy16(gb0, BsB0);
      async_copy16(gb1, BsB1);
      gb0 += 32; gb1 += 32;
      __syncthreads();
      mfma_tile(As, Bs, wm, wn, quad, lr, acc);
      __syncthreads();
    }
  }

  // epilogue: C/D layout col=lane&15, row=quad*4+reg; bf16 output
  const int colb = nt * 128 + wn * 64;
  const int rowb = mt * 128 + wm * 64 + quad * 4;
#pragma unroll
  for (int ni = 0; ni < 4; ++ni) {
    const int col = colb + ni * 16 + lr;
    const float bv = bias[col];
#pragma unroll
    for (int mi = 0; mi < 4; ++mi) {
      const int row = rowb + mi * 16;
#pragma unroll
      for (int r = 0; r < 4; ++r)
        Cout[(size_t)(row + r) * MID_ + col] = (__bf16)(acc[mi][ni][r] + bv);
    }
  }
}

// ---------------------------------------------------------------------------
// K3: per-(t,p): 4 dots over MID=256 (bf16 q/k), softmax over 4,
// out = pooled + sum attn*window, all values from fp32 img (L3-warm).
__global__ void attn_out_kernel(const __bf16* __restrict__ Qb,
                                const __bf16* __restrict__ Kb,
                                const float* __restrict__ img,
                                float* __restrict__ out) {
  const int pair = blockIdx.x;
  const int tid = threadIdx.x;
  const int wv = tid >> 6, lane = tid & 63;
  __shared__ float red[4][4];

  const int t = pair / P_;
  const int pp = pair - t * P_;
  const int wy = pp / 12, wx = pp - wy * 12;
  const float* base = img + ((size_t)t * 576 + 48 * wy + 2 * wx) * C_;
  const int c = tid * 4;
  f32x4 v0 = *(const f32x4*)(base + c);
  f32x4 v1 = *(const f32x4*)(base + (size_t)1 * C_ + c);
  f32x4 v2 = *(const f32x4*)(base + (size_t)24 * C_ + c);
  f32x4 v3 = *(const f32x4*)(base + (size_t)25 * C_ + c);

  const float qv = (float)Qb[(size_t)pair * MID_ + tid];
#pragma unroll
  for (int w = 0; w < 4; ++w) {
    float p = qv * (float)Kb[((size_t)pair * 4 + w) * MID_ + tid];
    p += __shfl_down(p, 32);
    p += __shfl_down(p, 16);
    p += __shfl_down(p, 8);
    p += __shfl_down(p, 4);
    p += __shfl_down(p, 2);
    p += __shfl_down(p, 1);
    if (lane == 0) red[w][wv] = p;
  }
  __syncthreads();
  float lg[4];
  float mx = -1e30f;
#pragma unroll
  for (int w = 0; w < 4; ++w) {
    lg[w] = (red[w][0] + red[w][1] + red[w][2] + red[w][3]) * 0.0625f;
    mx = fmaxf(mx, lg[w]);
  }
  float att[4];
  float ssum = 0.f;
#pragma unroll
  for (int w = 0; w < 4; ++w) {
    att[w] = __expf(lg[w] - mx);
    ssum += att[w];
  }
  const float inv = 1.f / ssum;
  const float a0 = att[0] * inv, a1 = att[1] * inv;
  const float a2 = att[2] * inv, a3 = att[3] * inv;

  f32x4 o = (v0 + v1 + v2 + v3) * 0.25f;
  o += a0 * v0 + a1 * v1 + a2 * v2 + a3 * v3;
  *(f32x4*)(out + (size_t)pair * C_ + c) = o;
}

// ---------------------------------------------------------------------------
extern "C" void kernel_launch(void* const* d_in, const int* in_sizes, int n_in,
                              void* d_out, int out_size, void* d_ws,
                              size_t ws_size, hipStream_t stream) {
  const float* img = (const float*)d_in[0];
  const float* Wq = (const float*)d_in[1];
  const float* bq = (const float*)d_in[2];
  const float* Wk = (const float*)d_in[3];
  const float* bk = (const float*)d_in[4];
  float* out = (float*)d_out;

  // workspace layout (total 43,515,904 B)
  char* ws = (char*)d_ws;
  __bf16* poolb = (__bf16*)ws;                 //  9216*1024*2 = 18,874,368
  __bf16* Wqt = (__bf16*)(ws + 18874368);      //   256*1024*2 =    524,288
  __bf16* Wkt = (__bf16*)(ws + 19398656);      //   256*1024*2 =    524,288
  __bf16* Qb = (__bf16*)(ws + 19922944);       //  9216*256*2  =  4,718,592
  __bf16* Kb = (__bf16*)(ws + 24641536);       // 36864*256*2  = 18,874,368

  prep_kernel<<<NPAIR + 512, 256, 0, stream>>>(img, Wq, Wk, poolb, Wqt, Wkt);
  gemm_qk_kernel<<<720, 256, 0, stream>>>(poolb, img, Wqt, Wkt, bq, bk, Qb, Kb);
  attn_out_kernel<<<NPAIR, 256, 0, stream>>>(Qb, Kb, img, out);
}

// Round 3
// 308.970 us; speedup vs baseline: 1.0196x; 1.0196x over previous
//
#include <hip/hip_runtime.h>

// Problem constants
#define T_ 64
#define P_ 144          // 12*12 windows per frame
#define NPAIR 9216      // T_*P_
#define C_ 1024
#define MID_ 256

typedef __attribute__((ext_vector_type(4))) float f32x4;
typedef __attribute__((ext_vector_type(8))) __bf16 bf16x8;
typedef __attribute__((ext_vector_type(4))) __bf16 bf16x4;

__device__ __forceinline__ void async_copy16(const void* g, void* l) {
  __builtin_amdgcn_global_load_lds(
      (const __attribute__((address_space(1))) unsigned int*)g,
      (__attribute__((address_space(3))) unsigned int*)l, 16, 0, 0);
}

// ---------------------------------------------------------------------------
// K1: blocks [0,NPAIR): mean-pool 2x2 windows -> pooled bf16.
//     blocks [NPAIR, NPAIR+256): convert Wq,Wk fp32 -> bf16 (same layout).
//     blocks [NPAIR+256, NPAIR+260): kb = Wk @ bq  [1024] fp32.
__global__ void prep_kernel(const float* __restrict__ img,
                            const float* __restrict__ Wq,
                            const float* __restrict__ bq,
                            const float* __restrict__ Wk,
                            __bf16* __restrict__ poolb,
                            __bf16* __restrict__ Wqb,
                            __bf16* __restrict__ Wkb,
                            float* __restrict__ kb) {
  const int bid = blockIdx.x;
  const int tid = threadIdx.x;
  if (bid < NPAIR) {
    const int t = bid / P_;
    const int p = bid - t * P_;
    const int wy = p / 12, wx = p - wy * 12;
    const int c = tid * 4;
    const float* base = img + ((size_t)t * 576 + 48 * wy + 2 * wx) * C_;
    f32x4 s = *(const f32x4*)(base + c);
    s += *(const f32x4*)(base + (size_t)1 * C_ + c);
    s += *(const f32x4*)(base + (size_t)24 * C_ + c);
    s += *(const f32x4*)(base + (size_t)25 * C_ + c);
    s *= 0.25f;
    bf16x4 pv;
#pragma unroll
    for (int j = 0; j < 4; ++j) pv[j] = (__bf16)s[j];
    *(bf16x4*)(poolb + (size_t)bid * C_ + c) = pv;
  } else if (bid < NPAIR + 256) {
    // convert 1024 contiguous elements of each weight matrix
    const int c0 = (bid - NPAIR) * 1024 + tid * 4;
    f32x4 q = *(const f32x4*)(Wq + c0);
    f32x4 k = *(const f32x4*)(Wk + c0);
    bf16x4 qb, kbv;
#pragma unroll
    for (int j = 0; j < 4; ++j) { qb[j] = (__bf16)q[j]; kbv[j] = (__bf16)k[j]; }
    *(bf16x4*)(Wqb + c0) = qb;
    *(bf16x4*)(Wkb + c0) = kbv;
  } else {
    __shared__ float bqs[256];
    bqs[tid] = bq[tid];
    __syncthreads();
    const int n = (bid - (NPAIR + 256)) * 256 + tid;
    const float* row = Wk + (size_t)n * MID_;
    float s = 0.f;
#pragma unroll 4
    for (int j = 0; j < 256; ++j) s += row[j] * bqs[j];
    kb[n] = s;
  }
}

// ---------------------------------------------------------------------------
// Generic 128x128-tile bf16 GEMM (m97 pattern): C[m][n] = sum_k A[m][k]*Bt[n][k]
// (+ bias[n]).  K multiple of 32, grid = mtiles*ntiles blocks of 256 threads.
template <typename OutT, bool HasBias>
__global__ __launch_bounds__(256) void gemm_kernel(
    const __bf16* __restrict__ A, const __bf16* __restrict__ Bt,
    const float* __restrict__ bias, OutT* __restrict__ C,
    int K, int ntiles, int ldc) {
  __shared__ __align__(16) __bf16 As[128 * 32];
  __shared__ __align__(16) __bf16 Bs[128 * 32];
  const int bid = blockIdx.x;
  const int mt = bid / ntiles, nt = bid - mt * ntiles;
  const int tid = threadIdx.x;
  const int lane = tid & 63;
  const int wv = tid >> 6;
  const int quad = lane >> 4, lr = lane & 15;
  const int wm = wv >> 1, wn = wv & 1;

  const int r0 = tid >> 2, p0 = tid & 3;  // row r0 (+64), 16B piece p0
  const int wvb = (tid & ~63) * 16;       // wave-uniform LDS byte offset
  const __bf16* ga0 = A + ((size_t)mt * 128 + r0) * (size_t)K + p0 * 8;
  const __bf16* ga1 = ga0 + (size_t)64 * K;
  const __bf16* gb0 = Bt + ((size_t)nt * 128 + r0) * (size_t)K + p0 * 8;
  const __bf16* gb1 = gb0 + (size_t)64 * K;
  char* AsB0 = (char*)As + wvb;
  char* AsB1 = (char*)As + 4096 + wvb;
  char* BsB0 = (char*)Bs + wvb;
  char* BsB1 = (char*)Bs + 4096 + wvb;

  f32x4 acc[4][4] = {};
  const int iters = K >> 5;

  for (int it = 0; it < iters; ++it) {
    async_copy16(ga0, AsB0);
    async_copy16(ga1, AsB1);
    async_copy16(gb0, BsB0);
    async_copy16(gb1, BsB1);
    ga0 += 32; ga1 += 32; gb0 += 32; gb1 += 32;
    __syncthreads();

    bf16x8 a[4], b[4];
    const bf16x8* Ap = (const bf16x8*)As;
    const bf16x8* Bp = (const bf16x8*)Bs;
#pragma unroll
    for (int i = 0; i < 4; ++i) {
      a[i] = Ap[(wm * 64 + i * 16 + lr) * 4 + quad];
      b[i] = Bp[(wn * 64 + i * 16 + lr) * 4 + quad];
    }
#pragma unroll
    for (int mi = 0; mi < 4; ++mi)
#pragma unroll
      for (int ni = 0; ni < 4; ++ni)
        acc[mi][ni] = __builtin_amdgcn_mfma_f32_16x16x32_bf16(
            a[mi], b[ni], acc[mi][ni], 0, 0, 0);
    __syncthreads();
  }

  // epilogue: C/D layout col=lane&15, row=quad*4+reg
  const int colb = nt * 128 + wn * 64;
  const int rowb = mt * 128 + wm * 64 + quad * 4;
#pragma unroll
  for (int ni = 0; ni < 4; ++ni) {
    const int col = colb + ni * 16 + lr;
    const float bv = HasBias ? bias[col] : 0.f;
#pragma unroll
    for (int mi = 0; mi < 4; ++mi) {
      const int row = rowb + mi * 16;
#pragma unroll
      for (int r = 0; r < 4; ++r)
        C[(size_t)(row + r) * ldc + col] = (OutT)(acc[mi][ni][r] + bv);
    }
  }
}

// ---------------------------------------------------------------------------
// K4: per-(t,p): logits_w = (u+kb already folded)·v_w * scale, softmax over 4,
// out = pooled + sum attn*window; v from fp32 img (L3-warm).
__global__ void attn_out_kernel(const float* __restrict__ U,
                                const float* __restrict__ img,
                                float* __restrict__ out) {
  const int pair = blockIdx.x;
  const int tid = threadIdx.x;
  const int wv = tid >> 6, lane = tid & 63;
  __shared__ float red[4][4];

  const int t = pair / P_;
  const int pp = pair - t * P_;
  const int wy = pp / 12, wx = pp - wy * 12;
  const float* base = img + ((size_t)t * 576 + 48 * wy + 2 * wx) * C_;
  const int c = tid * 4;
  f32x4 v0 = *(const f32x4*)(base + c);
  f32x4 v1 = *(const f32x4*)(base + (size_t)1 * C_ + c);
  f32x4 v2 = *(const f32x4*)(base + (size_t)24 * C_ + c);
  f32x4 v3 = *(const f32x4*)(base + (size_t)25 * C_ + c);
  const f32x4 u4 = *(const f32x4*)(U + (size_t)pair * C_ + c);

  float pd[4];
#pragma unroll
  for (int j = 0; j < 4; ++j) {
    // accumulate per-window partial dots
  }
  pd[0] = u4[0] * v0[0] + u4[1] * v0[1] + u4[2] * v0[2] + u4[3] * v0[3];
  pd[1] = u4[0] * v1[0] + u4[1] * v1[1] + u4[2] * v1[2] + u4[3] * v1[3];
  pd[2] = u4[0] * v2[0] + u4[1] * v2[1] + u4[2] * v2[2] + u4[3] * v2[3];
  pd[3] = u4[0] * v3[0] + u4[1] * v3[1] + u4[2] * v3[2] + u4[3] * v3[3];

#pragma unroll
  for (int w = 0; w < 4; ++w) {
    float p = pd[w];
    p += __shfl_down(p, 32);
    p += __shfl_down(p, 16);
    p += __shfl_down(p, 8);
    p += __shfl_down(p, 4);
    p += __shfl_down(p, 2);
    p += __shfl_down(p, 1);
    if (lane == 0) red[w][wv] = p;
  }
  __syncthreads();
  float lg[4];
  float mx = -1e30f;
#pragma unroll
  for (int w = 0; w < 4; ++w) {
    lg[w] = (red[w][0] + red[w][1] + red[w][2] + red[w][3]) * 0.0625f;
    mx = fmaxf(mx, lg[w]);
  }
  float att[4];
  float ssum = 0.f;
#pragma unroll
  for (int w = 0; w < 4; ++w) {
    att[w] = __expf(lg[w] - mx);
    ssum += att[w];
  }
  const float inv = 1.f / ssum;
  const float a0 = att[0] * inv, a1 = att[1] * inv;
  const float a2 = att[2] * inv, a3 = att[3] * inv;

  f32x4 o = (v0 + v1 + v2 + v3) * 0.25f;
  o += a0 * v0 + a1 * v1 + a2 * v2 + a3 * v3;
  *(f32x4*)(out + (size_t)pair * C_ + c) = o;
}

// ---------------------------------------------------------------------------
extern "C" void kernel_launch(void* const* d_in, const int* in_sizes, int n_in,
                              void* d_out, int out_size, void* d_ws,
                              size_t ws_size, hipStream_t stream) {
  const float* img = (const float*)d_in[0];
  const float* Wq = (const float*)d_in[1];
  const float* bq = (const float*)d_in[2];
  const float* Wk = (const float*)d_in[3];
  const float* bk = (const float*)d_in[4];  // unused: constant in softmax
  (void)bk;
  float* out = (float*)d_out;

  // workspace layout (~59.8 MB)
  char* ws = (char*)d_ws;
  __bf16* poolb = (__bf16*)ws;               //  9216*1024*2 = 18,874,368
  __bf16* Wqb = (__bf16*)(ws + 18874368);    //  1024*256*2  =    524,288
  __bf16* Wkb = (__bf16*)(ws + 19398656);    //  1024*256*2  =    524,288
  __bf16* H = (__bf16*)(ws + 19922944);      //  1024*1024*2 =  2,097,152
  float* kb = (float*)(ws + 22020096);       //  1024*4      =      4,096
  float* U = (float*)(ws + 22024192);        //  9216*1024*4 = 37,748,736

  // 1) pool + weight convert + kb
  prep_kernel<<<NPAIR + 260, 256, 0, stream>>>(img, Wq, bq, Wk, poolb, Wqb,
                                               Wkb, kb);
  // 2) H[n][k] = sum_j Wk[n][j] * Wq[k][j]   (1024x1024, K=256)
  gemm_kernel<__bf16, false><<<64, 256, 0, stream>>>(Wkb, Wqb, nullptr, H,
                                                     MID_, 8, C_);
  // 3) U[p][n] = sum_k pooled[p][k] * H[n][k] + kb[n]   (9216x1024, K=1024)
  gemm_kernel<float, true><<<576, 256, 0, stream>>>(poolb, H, kb, U, C_, 8,
                                                    C_);
  // 4) logits from U and img windows, softmax, weighted output
  attn_out_kernel<<<NPAIR, 256, 0, stream>>>(U, img, out);
}

// Round 4
// 294.984 us; speedup vs baseline: 1.0680x; 1.0474x over previous
//
#include <hip/hip_runtime.h>

// Problem constants
#define T_ 64
#define P_ 144          // 12*12 windows per frame
#define NPAIR 9216      // T_*P_
#define C_ 1024
#define MID_ 256

typedef __attribute__((ext_vector_type(4))) float f32x4;
typedef __attribute__((ext_vector_type(8))) __bf16 bf16x8;
typedef __attribute__((ext_vector_type(4))) __bf16 bf16x4;

__device__ __forceinline__ void async_copy16(const void* g, void* l) {
  __builtin_amdgcn_global_load_lds(
      (const __attribute__((address_space(1))) unsigned int*)g,
      (__attribute__((address_space(3))) unsigned int*)l, 16, 0, 0);
}

// ---------------------------------------------------------------------------
// shared MFMA tile step (128x128, BK=32, 4 waves 2x2, 4x4 frags)
__device__ __forceinline__ void mfma_tile(const __bf16* As, const __bf16* Bs,
                                          int wm, int wn, int quad, int lr,
                                          f32x4 acc[4][4]) {
  bf16x8 a[4], b[4];
  const bf16x8* Ap = (const bf16x8*)As;
  const bf16x8* Bp = (const bf16x8*)Bs;
#pragma unroll
  for (int i = 0; i < 4; ++i) {
    a[i] = Ap[(wm * 64 + i * 16 + lr) * 4 + quad];
    b[i] = Bp[(wn * 64 + i * 16 + lr) * 4 + quad];
  }
#pragma unroll
  for (int mi = 0; mi < 4; ++mi)
#pragma unroll
    for (int ni = 0; ni < 4; ++ni)
      acc[mi][ni] = __builtin_amdgcn_mfma_f32_16x16x32_bf16(
          a[mi], b[ni], acc[mi][ni], 0, 0, 0);
}

// ---------------------------------------------------------------------------
// K1 (fused prep):
//   blocks [0, NPAIR): mean-pool 2x2 windows -> pooled bf16
//   blocks [NPAIR, NPAIR+64): H = Wk @ Wq^T  [1024x1024] bf16
//       (128x128 tiles, K=256, inline fp32->bf16 register staging)
//   blocks [NPAIR+64, NPAIR+68): kb = Wk @ bq  [1024] fp32
__global__ __launch_bounds__(256) void prep_kernel(
    const float* __restrict__ img, const float* __restrict__ Wq,
    const float* __restrict__ bq, const float* __restrict__ Wk,
    __bf16* __restrict__ poolb, __bf16* __restrict__ H,
    float* __restrict__ kb) {
  __shared__ __align__(16) __bf16 As[128 * 32];
  __shared__ __align__(16) __bf16 Bs[128 * 32];
  const int bid = blockIdx.x;
  const int tid = threadIdx.x;
  if (bid < NPAIR) {
    const int t = bid / P_;
    const int p = bid - t * P_;
    const int wy = p / 12, wx = p - wy * 12;
    const int c = tid * 4;
    const float* base = img + ((size_t)t * 576 + 48 * wy + 2 * wx) * C_;
    f32x4 s = *(const f32x4*)(base + c);
    s += *(const f32x4*)(base + (size_t)1 * C_ + c);
    s += *(const f32x4*)(base + (size_t)24 * C_ + c);
    s += *(const f32x4*)(base + (size_t)25 * C_ + c);
    s *= 0.25f;
    bf16x4 pv;
#pragma unroll
    for (int j = 0; j < 4; ++j) pv[j] = (__bf16)s[j];
    *(bf16x4*)(poolb + (size_t)bid * C_ + c) = pv;
  } else if (bid < NPAIR + 64) {
    // H[m][n] = sum_j Wk[m][j] * Wq[n][j], m,n in 1024, j in 256
    const int b = bid - NPAIR;
    const int mt = b >> 3, nt = b & 7;
    const int lane = tid & 63;
    const int wv = tid >> 6;
    const int quad = lane >> 4, lr = lane & 15;
    const int wm = wv >> 1, wn = wv & 1;
    const int r0 = tid >> 2, p0 = tid & 3;
    const float* ga0 = Wk + (size_t)(mt * 128 + r0) * MID_ + p0 * 8;
    const float* ga1 = ga0 + (size_t)64 * MID_;
    const float* gb0 = Wq + (size_t)(nt * 128 + r0) * MID_ + p0 * 8;
    const float* gb1 = gb0 + (size_t)64 * MID_;
    f32x4 acc[4][4] = {};
    for (int it = 0; it < 8; ++it) {
      const f32x4 a0 = *(const f32x4*)ga0, a1 = *(const f32x4*)(ga0 + 4);
      const f32x4 a2 = *(const f32x4*)ga1, a3 = *(const f32x4*)(ga1 + 4);
      const f32x4 b0 = *(const f32x4*)gb0, b1 = *(const f32x4*)(gb0 + 4);
      const f32x4 b2 = *(const f32x4*)gb1, b3 = *(const f32x4*)(gb1 + 4);
      ga0 += 32; ga1 += 32; gb0 += 32; gb1 += 32;
      bf16x8 ca0, ca1, cb0, cb1;
#pragma unroll
      for (int j = 0; j < 4; ++j) {
        ca0[j] = (__bf16)a0[j]; ca0[4 + j] = (__bf16)a1[j];
        ca1[j] = (__bf16)a2[j]; ca1[4 + j] = (__bf16)a3[j];
        cb0[j] = (__bf16)b0[j]; cb0[4 + j] = (__bf16)b1[j];
        cb1[j] = (__bf16)b2[j]; cb1[4 + j] = (__bf16)b3[j];
      }
      *(bf16x8*)(As + (size_t)tid * 8) = ca0;
      *(bf16x8*)(As + (size_t)(tid + 256) * 8) = ca1;
      *(bf16x8*)(Bs + (size_t)tid * 8) = cb0;
      *(bf16x8*)(Bs + (size_t)(tid + 256) * 8) = cb1;
      __syncthreads();
      mfma_tile(As, Bs, wm, wn, quad, lr, acc);
      __syncthreads();
    }
    const int colb = nt * 128 + wn * 64;
    const int rowb = mt * 128 + wm * 64 + quad * 4;
#pragma unroll
    for (int ni = 0; ni < 4; ++ni) {
      const int col = colb + ni * 16 + lr;
#pragma unroll
      for (int mi = 0; mi < 4; ++mi) {
        const int row = rowb + mi * 16;
#pragma unroll
        for (int r = 0; r < 4; ++r)
          H[(size_t)(row + r) * C_ + col] = (__bf16)acc[mi][ni][r];
      }
    }
  } else {
    __shared__ float bqs[256];
    bqs[tid] = bq[tid];
    __syncthreads();
    const int n = (bid - (NPAIR + 64)) * 256 + tid;
    const float* row = Wk + (size_t)n * MID_;
    float s = 0.f;
#pragma unroll 4
    for (int j = 0; j < 256; ++j) s += row[j] * bqs[j];
    kb[n] = s;
  }
}

// ---------------------------------------------------------------------------
// K2: U[p][n] = sum_k pooled[p][k]*H[n][k] + kb[n]  -> bf16  (9216x1024,K=1024)
// m97 pattern: 128x128 tile, BK=32, global_load_lds width-16 staging.
__global__ __launch_bounds__(256) void gemm_u_kernel(
    const __bf16* __restrict__ A, const __bf16* __restrict__ Bt,
    const float* __restrict__ bias, __bf16* __restrict__ C) {
  __shared__ __align__(16) __bf16 As[128 * 32];
  __shared__ __align__(16) __bf16 Bs[128 * 32];
  const int bid = blockIdx.x;
  const int mt = bid >> 3, nt = bid & 7;  // consecutive bids share A-tile
  const int tid = threadIdx.x;
  const int lane = tid & 63;
  const int wv = tid >> 6;
  const int quad = lane >> 4, lr = lane & 15;
  const int wm = wv >> 1, wn = wv & 1;

  const int r0 = tid >> 2, p0 = tid & 3;
  const int wvb = (tid & ~63) * 16;  // wave-uniform LDS byte offset
  const __bf16* ga0 = A + ((size_t)mt * 128 + r0) * (size_t)C_ + p0 * 8;
  const __bf16* ga1 = ga0 + (size_t)64 * C_;
  const __bf16* gb0 = Bt + ((size_t)nt * 128 + r0) * (size_t)C_ + p0 * 8;
  const __bf16* gb1 = gb0 + (size_t)64 * C_;
  char* AsB0 = (char*)As + wvb;
  char* AsB1 = (char*)As + 4096 + wvb;
  char* BsB0 = (char*)Bs + wvb;
  char* BsB1 = (char*)Bs + 4096 + wvb;

  f32x4 acc[4][4] = {};

  for (int it = 0; it < 32; ++it) {
    async_copy16(ga0, AsB0);
    async_copy16(ga1, AsB1);
    async_copy16(gb0, BsB0);
    async_copy16(gb1, BsB1);
    ga0 += 32; ga1 += 32; gb0 += 32; gb1 += 32;
    __syncthreads();
    mfma_tile(As, Bs, wm, wn, quad, lr, acc);
    __syncthreads();
  }

  const int colb = nt * 128 + wn * 64;
  const int rowb = mt * 128 + wm * 64 + quad * 4;
#pragma unroll
  for (int ni = 0; ni < 4; ++ni) {
    const int col = colb + ni * 16 + lr;
    const float bv = bias[col];
#pragma unroll
    for (int mi = 0; mi < 4; ++mi) {
      const int row = rowb + mi * 16;
#pragma unroll
      for (int r = 0; r < 4; ++r)
        C[(size_t)(row + r) * C_ + col] = (__bf16)(acc[mi][ni][r] + bv);
    }
  }
}

// ---------------------------------------------------------------------------
// K3: per-(t,p): logit_w = (u·v_w)*scale, softmax over 4,
// out = pooled + sum attn*window; v from fp32 img (L3-warm), u bf16.
__global__ void attn_out_kernel(const __bf16* __restrict__ U,
                                const float* __restrict__ img,
                                float* __restrict__ out) {
  const int pair = blockIdx.x;
  const int tid = threadIdx.x;
  const int wv = tid >> 6, lane = tid & 63;
  __shared__ float red[4][4];

  const int t = pair / P_;
  const int pp = pair - t * P_;
  const int wy = pp / 12, wx = pp - wy * 12;
  const float* base = img + ((size_t)t * 576 + 48 * wy + 2 * wx) * C_;
  const int c = tid * 4;
  f32x4 v0 = *(const f32x4*)(base + c);
  f32x4 v1 = *(const f32x4*)(base + (size_t)1 * C_ + c);
  f32x4 v2 = *(const f32x4*)(base + (size_t)24 * C_ + c);
  f32x4 v3 = *(const f32x4*)(base + (size_t)25 * C_ + c);
  const bf16x4 ub = *(const bf16x4*)(U + (size_t)pair * C_ + c);
  f32x4 u4;
#pragma unroll
  for (int j = 0; j < 4; ++j) u4[j] = (float)ub[j];

  float pd[4];
  pd[0] = u4[0] * v0[0] + u4[1] * v0[1] + u4[2] * v0[2] + u4[3] * v0[3];
  pd[1] = u4[0] * v1[0] + u4[1] * v1[1] + u4[2] * v1[2] + u4[3] * v1[3];
  pd[2] = u4[0] * v2[0] + u4[1] * v2[1] + u4[2] * v2[2] + u4[3] * v2[3];
  pd[3] = u4[0] * v3[0] + u4[1] * v3[1] + u4[2] * v3[2] + u4[3] * v3[3];

#pragma unroll
  for (int w = 0; w < 4; ++w) {
    float p = pd[w];
    p += __shfl_down(p, 32);
    p += __shfl_down(p, 16);
    p += __shfl_down(p, 8);
    p += __shfl_down(p, 4);
    p += __shfl_down(p, 2);
    p += __shfl_down(p, 1);
    if (lane == 0) red[w][wv] = p;
  }
  __syncthreads();
  float lg[4];
  float mx = -1e30f;
#pragma unroll
  for (int w = 0; w < 4; ++w) {
    lg[w] = (red[w][0] + red[w][1] + red[w][2] + red[w][3]) * 0.0625f;
    mx = fmaxf(mx, lg[w]);
  }
  float att[4];
  float ssum = 0.f;
#pragma unroll
  for (int w = 0; w < 4; ++w) {
    att[w] = __expf(lg[w] - mx);
    ssum += att[w];
  }
  const float inv = 1.f / ssum;
  const float a0 = att[0] * inv, a1 = att[1] * inv;
  const float a2 = att[2] * inv, a3 = att[3] * inv;

  f32x4 o = (v0 + v1 + v2 + v3) * 0.25f;
  o += a0 * v0 + a1 * v1 + a2 * v2 + a3 * v3;
  *(f32x4*)(out + (size_t)pair * C_ + c) = o;
}

// ---------------------------------------------------------------------------
extern "C" void kernel_launch(void* const* d_in, const int* in_sizes, int n_in,
                              void* d_out, int out_size, void* d_ws,
                              size_t ws_size, hipStream_t stream) {
  const float* img = (const float*)d_in[0];
  const float* Wq = (const float*)d_in[1];
  const float* bq = (const float*)d_in[2];
  const float* Wk = (const float*)d_in[3];
  const float* bk = (const float*)d_in[4];  // constant under softmax -> unused
  (void)bk;
  float* out = (float*)d_out;

  // workspace layout (~39.9 MB)
  char* ws = (char*)d_ws;
  __bf16* poolb = (__bf16*)ws;             //  9216*1024*2 = 18,874,368
  __bf16* H = (__bf16*)(ws + 18874368);    //  1024*1024*2 =  2,097,152
  float* kb = (float*)(ws + 20971520);     //  1024*4      =      4,096
  __bf16* U = (__bf16*)(ws + 20975616);    //  9216*1024*2 = 18,874,368

  // 1) pool + H + kb (independent sub-problems, one launch)
  prep_kernel<<<NPAIR + 68, 256, 0, stream>>>(img, Wq, bq, Wk, poolb, H, kb);
  // 2) U = pooled @ H^T + kb  (bf16 out)
  gemm_u_kernel<<<576, 256, 0, stream>>>(poolb, H, kb, U);
  // 3) logits from U and img windows, softmax, weighted output
  attn_out_kernel<<<NPAIR, 256, 0, stream>>>(U, img, out);
}